// Round 4
// baseline (334.866 us; speedup 1.0000x reference)
//
#include <hip/hip_runtime.h>
#include <math.h>

#define BB   2
#define SC   384
#define SH   112
#define SW   112
#define GH   224
#define GW   224
#define HWs  (SH*SW)     // 12544
#define HWg  (GH*GW)     // 50176
#define GT   22          // 16 + 2*3 guidance tile dim
#define NCB  2           // channel blocks
#define CPB  (SC/NCB)    // 192 channels per block

typedef float f32x2 __attribute__((ext_vector_type(2)));

__device__ __forceinline__ int reflect224(int v){
    v = v < 0 ? -v : v;
    v = v > 223 ? 446 - v : v;
    return v;
}

__launch_bounds__(256, 2)
__global__ void jbu_kernel(const float* __restrict__ src,
                           const float* __restrict__ gdn,
                           const float* __restrict__ sigs,
                           const float* __restrict__ sigr,
                           float* __restrict__ out)
{
    // LDS: 22*22*3*4 = 5808 B + 25*256*4 = 25600 B + 1024 B  => ~32.4 KB
    __shared__ float gtile[GT*GT*3];
    __shared__ float slab[25*256];
    __shared__ float invs_sh[256];

    const int bx = blockIdx.x;
    const int cb = bx / 392;             // 0..NCB-1
    const int r  = bx - cb*392;
    const int b  = r / 196;
    const int t  = r - b*196;
    const int th = t / 14, tw = t - th*14;
    const int h0 = th*16, w0 = tw*16;

    const int tid = threadIdx.x;

    const float ssv  = fabsf(sigs[0]);
    const float srv  = fabsf(sigr[0]);
    const float i2ss = 0.5f/(ssv*ssv);
    const float i2sr = 0.5f/(srv*srv);

    // zero the weight slab
    #pragma unroll
    for (int k=0;k<25;k++) slab[k*256+tid] = 0.f;

    // stage L2-normalized guidance tile, reflect applied at staging
    // (reference normalizes then reflect-pads; reflect is an index copy, so
    //  normalizing after reflected indexing is identical)
    const float* gb = gdn + (size_t)b*3*HWg;
    for (int idx = tid; idx < GT*GT; idx += 256){
        int ty = idx / GT, tx = idx - ty*GT;
        int y = reflect224(h0 - 3 + ty);
        int x = reflect224(w0 - 3 + tx);
        float g0 = gb[y*GW + x];
        float g1 = gb[HWg   + y*GW + x];
        float g2 = gb[2*HWg + y*GW + x];
        float nrm = sqrtf(g0*g0 + g1*g1 + g2*g2);
        float inv = 1.0f / fmaxf(nrm, 1e-12f);
        gtile[idx*3+0] = g0*inv;
        gtile[idx*3+1] = g1*inv;
        gtile[idx*3+2] = g2*inv;
    }
    __syncthreads();

    // ---- phase 1: per-pixel effective 5x5 source weights ----
    // Fold the x2 bilinear upsample (half-pixel centers) into the 49 bilateral
    // taps: hr row yr=reflect(h+i-3) = {0.25,0.75} mix of src rows
    // a-1+(yr&1), +1 where a=yr>>1. All contributions land in the 5x5 window
    // around (h>>1, w>>1); edge clamping in phase 2 reproduces
    // jax.image.resize's drop-and-renormalize boundary exactly.
    const int hh = tid >> 4, ww = tid & 15;
    const int h = h0 + hh, w = w0 + ww;
    const float c0 = gtile[((hh+3)*GT + (ww+3))*3 + 0];
    const float c1 = gtile[((hh+3)*GT + (ww+3))*3 + 1];
    const float c2 = gtile[((hh+3)*GT + (ww+3))*3 + 2];

    // per-j column tap info (fully unrolled -> registers)
    float wc0a[7]; int dc0a[7];
    #pragma unroll
    for (int j=0;j<7;j++){
        int xr = reflect224(w + j - 3);
        int a  = xr >> 1;
        int cs0 = a - 1 + (xr & 1);          // first src col of bilinear pair
        wc0a[j] = (xr & 1) ? 0.75f : 0.25f;  // its weight; second gets 1-w
        dc0a[j] = cs0 - ((w>>1) - 2);        // window slot, always in [0,3]
    }

    float sum = 0.f;
    #pragma unroll
    for (int i=0;i<7;i++){
        int yr = reflect224(h + i - 3);
        int a  = yr >> 1;
        int rs0 = a - 1 + (yr & 1);
        float wr0 = (yr & 1) ? 0.75f : 0.25f;
        int dr0 = rs0 - ((h>>1) - 2);        // row slot, always in [0,3]
        const float* grow = &gtile[((hh+i)*GT + ww)*3];
        float di2 = (float)((i-3)*(i-3));
        #pragma unroll
        for (int j=0;j<7;j++){
            float dot = c0*grow[j*3+0] + c1*grow[j*3+1] + c2*grow[j*3+2];
            float t2  = 2.0f - dot;
            float dj2 = (float)((j-3)*(j-3));
            float ck  = expf(-(t2*t2*i2sr + (di2+dj2)*i2ss));
            sum += ck;
            float p0 = ck*wr0, p1 = ck - p0;
            float wc0 = wc0a[j];
            float q00 = p0*wc0, q01 = p0 - q00;
            float q10 = p1*wc0, q11 = p1 - q10;
            int base = (dr0*5 + dc0a[j])*256 + tid;   // column [tid] thread-exclusive
            slab[base        ] += q00;
            slab[base +   256] += q01;
            slab[base + 5*256] += q10;
            slab[base + 6*256] += q11;
        }
    }
    invs_sh[tid] = 1.0f / fmaxf(sum, 1e-7f);
    __syncthreads();

    // ---- phase 2: adaptive 5x5 conv over all channels ----
    const int wid  = tid >> 6, lane = tid & 63;
    const int wm   = lane >> 3, wn = lane & 7;
    const int m    = th*8 + wm, n = tw*8 + wn;   // shared src window (2x2 out px)

    // 2x2-pixel-group effective weights -> registers (100 VGPRs)
    float wf[4][25];
    #pragma unroll
    for (int q=0;q<4;q++){
        int e = q>>1, f = q&1;
        int px = (2*wm+e)*16 + (2*wn+f);
        float inv = invs_sh[px];
        #pragma unroll
        for (int k=0;k<25;k++) wf[q][k] = slab[k*256+px]*inv;
    }

    // per-lane byte offsets into a source channel plane (edge-clamped)
    int voff[25];
    #pragma unroll
    for (int dr=0;dr<5;dr++){
        int sr_ = m - 2 + dr; sr_ = sr_ < 0 ? 0 : (sr_ > SH-1 ? SH-1 : sr_);
        #pragma unroll
        for (int dc=0;dc<5;dc++){
            int sc_ = n - 2 + dc; sc_ = sc_ < 0 ? 0 : (sc_ > SW-1 ? SW-1 : sc_);
            voff[dr*5+dc] = (sr_*SW + sc_)*4;
        }
    }
    const int ooffB = ((2*m)*GW + 2*n)*4;

    const int wid_u = __builtin_amdgcn_readfirstlane(wid);  // SGPR base chains

    for (int it = 0; it < CPB/4; ++it){
        int c = cb*CPB + wid_u + it*4;
        const char* sb = (const char*)(src + (size_t)(b*SC + c)*HWs);
        float v[25];
        #pragma unroll
        for (int k=0;k<25;k++) v[k] = *(const float*)(sb + voff[k]);
        float a0=0.f, a1=0.f, a2=0.f, a3=0.f;
        #pragma unroll
        for (int k=0;k<25;k++){
            a0 += wf[0][k]*v[k];
            a1 += wf[1][k]*v[k];
            a2 += wf[2][k]*v[k];
            a3 += wf[3][k]*v[k];
        }
        char* ob = (char*)(out + (size_t)(b*SC + c)*HWg) + ooffB;
        f32x2 r0 = {a0, a1};
        f32x2 r1 = {a2, a3};
        __builtin_nontemporal_store(r0, (f32x2*)ob);
        __builtin_nontemporal_store(r1, (f32x2*)(ob + GW*4));
    }
}

extern "C" void kernel_launch(void* const* d_in, const int* in_sizes, int n_in,
                              void* d_out, int out_size, void* d_ws, size_t ws_size,
                              hipStream_t stream) {
    (void)in_sizes; (void)n_in; (void)d_ws; (void)ws_size; (void)out_size;
    const float* src  = (const float*)d_in[0];
    const float* gdn  = (const float*)d_in[1];
    const float* sigs = (const float*)d_in[2];
    const float* sigr = (const float*)d_in[3];
    float* out = (float*)d_out;

    dim3 grid(NCB * BB * 196);   // 784 blocks
    dim3 block(256);
    jbu_kernel<<<grid, block, 0, stream>>>(src, gdn, sigs, sigr, out);
}